// Round 2
// baseline (60.552 us; speedup 1.0000x reference)
//
#include <hip/hip_runtime.h>

// Problem constants (B=8, U=512, F=64, R=256)
#define BU   4096      // B*U rows of x
#define F_   64
#define R_   256
#define ROWS_PER_BLOCK 16

// fp64 -> fp32 with flush-to-zero for denormal results, matching the
// XLA/GPU fp32 reference semantics (f32 denormals flushed). d >= 0.
// Since every factor <= 1, the reference's running product is non-increasing,
// so "final value < FLT_MIN  =>  reference produced 0" holds exactly.
__device__ __forceinline__ float d2f_ftz(double d) {
    return (d >= 0x1.0p-126) ? (float)d : 0.0f;
}

__global__ __launch_bounds__(256) void rules_outer_kernel(
        const float* __restrict__ x,        // [BU, F]
        const float* __restrict__ rules,    // [R, F]
        float* __restrict__ out)            // [BU, R]
{
    __shared__ double sPr[R_];
    __shared__ double sPx[ROWS_PER_BLOCK];

    const int t   = threadIdx.x;            // 0..255
    const int bu0 = blockIdx.x * ROWS_PER_BLOCK;

    // ---- Pr[t] = prod_f rules[t][f] in fp64 ----
    {
        const float4* rp = (const float4*)(rules + t * F_);
        double p = 1.0;
        #pragma unroll
        for (int i = 0; i < F_ / 4; ++i) {
            float4 v = rp[i];
            p *= (double)v.x; p *= (double)v.y;
            p *= (double)v.z; p *= (double)v.w;
        }
        sPr[t] = p;
    }

    // ---- Px[row] for this block's 16 rows ----
    if (t < ROWS_PER_BLOCK) {
        const float4* xp = (const float4*)(x + (size_t)(bu0 + t) * F_);
        double q = 1.0;
        #pragma unroll
        for (int i = 0; i < F_ / 4; ++i) {
            float4 v = xp[i];
            q *= (double)v.x; q *= (double)v.y;
            q *= (double)v.z; q *= (double)v.w;
        }
        sPx[t] = q;
    }
    __syncthreads();

    // ---- outer product tile: 16 rows x 256 cols, float4 stores ----
    const int c    = t & 63;                // column group (4 cols each)
    const int rowl = t >> 6;                // 0..3
    const int r0   = c * 4;

    // Pr values for this thread's 4 columns (invariant across rows)
    const double pr0 = sPr[r0 + 0];
    const double pr1 = sPr[r0 + 1];
    const double pr2 = sPr[r0 + 2];
    const double pr3 = sPr[r0 + 3];

    #pragma unroll
    for (int pass = 0; pass < 4; ++pass) {
        const int row = pass * 4 + rowl;
        const double px = sPx[row];
        float4 o;
        o.x = d2f_ftz(px * pr0);
        o.y = d2f_ftz(px * pr1);
        o.z = d2f_ftz(px * pr2);
        o.w = d2f_ftz(px * pr3);
        *(float4*)(out + (size_t)(bu0 + row) * R_ + r0) = o;
    }
}

extern "C" void kernel_launch(void* const* d_in, const int* in_sizes, int n_in,
                              void* d_out, int out_size, void* d_ws, size_t ws_size,
                              hipStream_t stream) {
    const float* x     = (const float*)d_in[0];   // [8,512,64]
    const float* rules = (const float*)d_in[1];   // [256,64]
    // d_in[2] = epoch (unused)
    float* out = (float*)d_out;                   // [8,512,256]

    rules_outer_kernel<<<BU / ROWS_PER_BLOCK, 256, 0, stream>>>(x, rules, out);
}